// Round 8
// baseline (34.388 us; speedup 1.0000x reference)
//
#include <hip/hip_runtime.h>

#define SEQ 128
#define SD  15
#define REC 32    // floats per (b,s) record in dba_params
#define RPB 4     // rows per block
#define NT  (RPB * SEQ)   // 512 threads, 8 waves

// ---------------------------------------------------------------------------
// Single fused kernel, no trailing barrier. Block = 4 batch rows.
//  P1 : thread (row,s) loads its record head (32 B of one 64 B line),
//       stores pre-scaled dq -> LDS, shuffle-scans positions in registers.
//  P2a: EVERY ready output byte is stored immediately: pos (3), zeros (8),
//       and the t=0 quat (s==0). 11/15 of write traffic is in flight
//       before/during the serial phase (R5 vs R6 showed this overlap is
//       worth more than the write-amplification it risks).
//  P2b: lanes 0..3 of wave 0 run the 127-step chains, reading dq through a
//       named-register double-buffered 8-wide window (immune to the array-
//       demotion that left R6 at 20 VGPRs) and storing quats DIRECTLY to
//       global — 4 scalar stores/step dual-issue into the chain's dependency
//       stalls. No squat LDS, no final __syncthreads: waves 1-7 retire as
//       soon as their stores issue, freeing slots so following blocks'
//       loads overlap resident blocks' chains.
// ---------------------------------------------------------------------------
__global__ __launch_bounds__(NT, 8) void fused_kernel(const float* __restrict__ dba,
                                                      const float* __restrict__ gt,
                                                      float* __restrict__ out,
                                                      int B) {
    const int tid  = threadIdx.x;
    const int row  = tid >> 7;          // 0..3
    const int s    = tid & (SEQ - 1);   // 0..127
    const int lane = tid & 63;
    const int half = s >> 6;            // which of the row's two waves
    const int r    = blockIdx.x * RPB + row;
    const bool valid = (r < B);

    __shared__ float4 sdq  [RPB][SEQ + 1];   // +1 pad: chain lanes on distinct banks
    __shared__ float  ginit[RPB][8];
    __shared__ float  w0tot[RPB][3];

    // ---- P1: loads + pos scan ----
    float d0 = 0.f, d1 = 0.f, d2 = 0.f;
    if (valid) {
        const float* rec = dba + ((size_t)r * SEQ + s) * REC;
        const float4 h0 = *reinterpret_cast<const float4*>(rec);
        const float4 h1 = *reinterpret_cast<const float4*>(rec + 4);
        sdq[row][s] = make_float4(h0.w * 0.1f, h1.x * 0.1f, h1.y * 0.1f, h1.z * 0.1f);
        d0 = h0.x * 0.1f; d1 = h0.y * 0.1f; d2 = h0.z * 0.1f;
        if (s == 0) {
            const float* g = gt + (size_t)r * SEQ * SD;
            *reinterpret_cast<float4*>(&ginit[row][0]) = *reinterpret_cast<const float4*>(g);
            *reinterpret_cast<float4*>(&ginit[row][4]) = *reinterpret_cast<const float4*>(g + 4);
        }
    }

    float ix = d0, iy = d1, iz = d2;       // wave-local inclusive scan
#pragma unroll
    for (int off = 1; off < 64; off <<= 1) {
        const float tx = __shfl_up(ix, off, 64);
        const float ty = __shfl_up(iy, off, 64);
        const float tz = __shfl_up(iz, off, 64);
        if (lane >= off) { ix += tx; iy += ty; iz += tz; }
    }
    if (half == 0 && lane == 63) {
        w0tot[row][0] = ix; w0tot[row][1] = iy; w0tot[row][2] = iz;
    }
    __syncthreads();
    if (half == 1) { ix += w0tot[row][0]; iy += w0tot[row][1]; iz += w0tot[row][2]; }

    // ---- P2a: store every ready byte now (pos, zeros, t=0 quat) ----
    if (valid) {
        float* o = out + ((size_t)r * SEQ + s) * SD;
        o[0] = ginit[row][0] + ix - d0;   // exclusive prefix = inclusive - own
        o[1] = ginit[row][1] + iy - d1;
        o[2] = ginit[row][2] + iz - d2;
        if (s == 0) {                     // t=0 quat: init_q, NOT normalized
            o[3] = ginit[row][3]; o[4] = ginit[row][4];
            o[5] = ginit[row][5]; o[6] = ginit[row][6];
        }
#pragma unroll
        for (int k = 7; k < SD; ++k) o[k] = 0.f;
    }

    // ---- P2b: quaternion chains, lanes 0..3 of wave 0, direct global stores ----
    if (tid < RPB && blockIdx.x * RPB + tid < B) {
        const float4* srow = sdq[tid];
        float* oq = out + ((size_t)(blockIdx.x * RPB + tid) * SEQ + 1) * SD + 3;
        float q0 = ginit[tid][3], q1 = ginit[tid][4],
              q2 = ginit[tid][5], q3 = ginit[tid][6];

#define QSTEP(C) do {                                                   \
            q0 += (C).x; q1 += (C).y; q2 += (C).z; q3 += (C).w;         \
            const float a_ = q0 * q0 + q1 * q1;                         \
            const float b_ = q2 * q2 + q3 * q3;                         \
            const float i_ = __builtin_amdgcn_rsqf(a_ + b_);            \
            q0 *= i_; q1 *= i_; q2 *= i_; q3 *= i_;                     \
            oq[0] = q0; oq[1] = q1; oq[2] = q2; oq[3] = q3;             \
            oq += SD;                                                   \
        } while (0)

        // Named double-buffered window: 8 dq in flight, refilled once per
        // 8 steps (~200 cyc of chain math hides ~120 cyc LDS latency).
        float4 c0 = srow[0], c1 = srow[1], c2 = srow[2], c3 = srow[3],
               c4 = srow[4], c5 = srow[5], c6 = srow[6], c7 = srow[7];
        for (int w = 0; w < 15; ++w) {               // t = 1..120
            const float4* nx = srow + (w + 1) * 8;   // last: srow[120..127]
            const float4 n0 = nx[0], n1 = nx[1], n2 = nx[2], n3 = nx[3],
                         n4 = nx[4], n5 = nx[5], n6 = nx[6], n7 = nx[7];
            QSTEP(c0); QSTEP(c1); QSTEP(c2); QSTEP(c3);
            QSTEP(c4); QSTEP(c5); QSTEP(c6); QSTEP(c7);
            c0 = n0; c1 = n1; c2 = n2; c3 = n3;
            c4 = n4; c5 = n5; c6 = n6; c7 = n7;
        }
        QSTEP(c0); QSTEP(c1); QSTEP(c2); QSTEP(c3);  // t = 121..127
        QSTEP(c4); QSTEP(c5); QSTEP(c6);
#undef QSTEP
    }
    // no trailing barrier — waves 1..7 retire here
}

extern "C" void kernel_launch(void* const* d_in, const int* in_sizes, int n_in,
                              void* d_out, int out_size, void* d_ws, size_t ws_size,
                              hipStream_t stream) {
    const float* dba = (const float*)d_in[0];   // (B, 128, 32)
    // d_in[1] = imu_measurements — unused by the reference
    const float* gt  = (const float*)d_in[2];   // (B, 128, 15)
    float* out = (float*)d_out;                 // (B, 128, 15)

    const int B = in_sizes[0] / (SEQ * REC);
    const int blocks = (B + RPB - 1) / RPB;
    fused_kernel<<<blocks, NT, 0, stream>>>(dba, gt, out, B);
}